// Round 1
// baseline (1077.337 us; speedup 1.0000x reference)
//
#include <hip/hip_runtime.h>

#define DD 128
static constexpr float SLOPE = (1.0f/8.0f + 1.0f/3.0f) * 0.5f;  // rrelu eval slope

__global__ __launch_bounds__(256) void set_flags_k(const int* __restrict__ dst,
                                                   int* __restrict__ flags, int E) {
    int i = blockIdx.x * 256 + threadIdx.x;
    if (i < E) flags[dst[i]] = 1;
}

// out[r,:] = A[r,:] @ W  (W is 128x128 row-major [k][c]).
// Rows: r < N read from h, N <= r < M read from rel (may be null when M==N).
__global__ __launch_bounds__(256) void gemm128_k(
    const float* __restrict__ h, const float* __restrict__ rel,
    const float* __restrict__ W, float* __restrict__ out_h,
    float* __restrict__ out_rel, int N, int M)
{
    __shared__ float Ws[DD * DD];   // 64 KB
    __shared__ float As[32 * DD];   // 16 KB, per-row rotation swizzle
    int tid = threadIdx.x;

    // stage W: 16384 floats = 16 float4 per thread
    for (int i = tid * 4; i < DD * DD; i += 256 * 4)
        *(float4*)&Ws[i] = *(const float4*)&W[i];

    // stage A tile (32 rows), rotate row lr by lr float4s to kill bank conflicts
    int row0 = blockIdx.x * 32;
    for (int i = tid; i < 32 * DD / 4; i += 256) {
        int lr = i >> 5;          // local row
        int c4 = i & 31;          // float4 column
        int r = row0 + lr;
        float4 v = make_float4(0.f, 0.f, 0.f, 0.f);
        if (r < N)       v = *(const float4*)&h[(size_t)r * DD + c4 * 4];
        else if (r < M)  v = *(const float4*)&rel[(size_t)(r - N) * DD + c4 * 4];
        int c4s = (c4 + lr) & 31;
        *(float4*)&As[lr * DD + c4s * 4] = v;
    }
    __syncthreads();

    int lr = tid >> 3;        // 0..31 local row
    int g  = tid & 7;         // colgroup: cols g*4 + 32*m, m=0..3
    float acc[16];
    #pragma unroll
    for (int j = 0; j < 16; j++) acc[j] = 0.f;

    #pragma unroll 4
    for (int k = 0; k < DD; k++) {
        float a = As[lr * DD + ((k + 4 * lr) & 127)];
        #pragma unroll
        for (int m = 0; m < 4; m++) {
            float4 w = *(const float4*)&Ws[k * DD + g * 4 + 32 * m];
            acc[m * 4 + 0] = fmaf(a, w.x, acc[m * 4 + 0]);
            acc[m * 4 + 1] = fmaf(a, w.y, acc[m * 4 + 1]);
            acc[m * 4 + 2] = fmaf(a, w.z, acc[m * 4 + 2]);
            acc[m * 4 + 3] = fmaf(a, w.w, acc[m * 4 + 3]);
        }
    }

    int r = row0 + lr;
    float* dstp;
    if (r < N)      dstp = out_h + (size_t)r * DD;
    else if (r < M) dstp = out_rel + (size_t)(r - N) * DD;
    else return;
    #pragma unroll
    for (int m = 0; m < 4; m++)
        *(float4*)&dstp[g * 4 + 32 * m] =
            make_float4(acc[m*4+0], acc[m*4+1], acc[m*4+2], acc[m*4+3]);
}

// Rows with indeg==0 (~2 of 50000) use W_evolve instead of W_loop.
__global__ void loop_fixup_k(const float* __restrict__ h, const float* __restrict__ We,
                             const int* __restrict__ flags, float* __restrict__ loopm,
                             int N) {
    int r = blockIdx.x;
    if (r >= N || flags[r]) return;
    int c = threadIdx.x;  // 128 threads
    float acc = 0.f;
    for (int k = 0; k < DD; k++)
        acc = fmaf(h[(size_t)r * DD + k], We[k * DD + c], acc);
    loopm[(size_t)r * DD + c] = acc;
}

// 4 edges per 256-thread block; each lane handles 2 floats of one edge.
__global__ __launch_bounds__(256) void edge_scatter_k(
    const float* __restrict__ hWn, const float* __restrict__ rW,
    const int* __restrict__ src, const int* __restrict__ dst,
    const int* __restrict__ rel, float* __restrict__ agg, int E)
{
    int t = blockIdx.x * 256 + threadIdx.x;
    int e = t >> 6;
    if (e >= E) return;
    int lane = t & 63;
    int s = src[e], d = dst[e], q = rel[e];
    float2 a = *(const float2*)&hWn[(size_t)s * DD + lane * 2];
    float2 b = *(const float2*)&rW[(size_t)q * DD + lane * 2];
    float* p = &agg[(size_t)d * DD + lane * 2];
    atomicAdd(p,     a.x + b.x);
    atomicAdd(p + 1, a.y + b.y);
}

__global__ __launch_bounds__(256) void finalize_k(
    const float* __restrict__ agg, const float* __restrict__ loopm,
    const float* __restrict__ norm, float* __restrict__ hout, int N)
{
    int i = blockIdx.x * 256 + threadIdx.x;  // float4 index
    int total = N * DD / 4;
    if (i >= total) return;
    int r = i >> 5;                          // 32 float4 per row
    float nv = norm[r];
    float4 av = *(const float4*)&agg[(size_t)i * 4];
    float4 lv = *(const float4*)&loopm[(size_t)i * 4];
    float4 o;
    o.x = av.x * nv + lv.x;
    o.y = av.y * nv + lv.y;
    o.z = av.z * nv + lv.z;
    o.w = av.w * nv + lv.w;
    o.x = o.x >= 0.f ? o.x : SLOPE * o.x;
    o.y = o.y >= 0.f ? o.y : SLOPE * o.y;
    o.z = o.z >= 0.f ? o.z : SLOPE * o.z;
    o.w = o.w >= 0.f ? o.w : SLOPE * o.w;
    *(float4*)&hout[(size_t)i * 4] = o;
}

extern "C" void kernel_launch(void* const* d_in, const int* in_sizes, int n_in,
                              void* d_out, int out_size, void* d_ws, size_t ws_size,
                              hipStream_t stream) {
    const float* node    = (const float*)d_in[0];
    const float* rel_emb = (const float*)d_in[1];
    const float* norm    = (const float*)d_in[2];
    const int*   esrc    = (const int*)d_in[3];
    const int*   edst    = (const int*)d_in[4];
    const int*   erel    = (const int*)d_in[5];
    const float* Wn      = (const float*)d_in[6];
    const float* Wl      = (const float*)d_in[7];
    const float* We      = (const float*)d_in[8];
    int N = in_sizes[0] / DD;
    int R = in_sizes[1] / DD;
    int E = in_sizes[3];
    float* out = (float*)d_out;

    char* w = (char*)d_ws;
    auto alloc = [&](size_t bytes) {
        void* p = (void*)w;
        w += (bytes + 255) & ~(size_t)255;
        return p;
    };
    int*   flags = (int*)  alloc((size_t)N * 4);
    float* rW    = (float*)alloc((size_t)R * DD * 4);
    float* hWn   = (float*)alloc((size_t)N * DD * 4);
    float* loopm = (float*)alloc((size_t)N * DD * 4);
    float* agg   = (float*)alloc((size_t)N * DD * 4);

    hipMemsetAsync(flags, 0, (size_t)N * 4, stream);
    set_flags_k<<<(E + 255) / 256, 256, 0, stream>>>(edst, flags, E);

    const float* hin = node;
    for (int l = 0; l < 2; l++) {
        int M = N + R;
        // hW = h @ Wn  and  rW = rel_emb @ Wn (same pass, rel rows appended)
        gemm128_k<<<(M + 31) / 32, 256, 0, stream>>>(
            hin, rel_emb, Wn + (size_t)l * DD * DD, hWn, rW, N, M);
        // loop_msg = h @ Wl (dense), evolve rows fixed up after
        gemm128_k<<<(N + 31) / 32, 256, 0, stream>>>(
            hin, nullptr, Wl + (size_t)l * DD * DD, loopm, nullptr, N, N);
        loop_fixup_k<<<N, DD, 0, stream>>>(
            hin, We + (size_t)l * DD * DD, flags, loopm, N);
        hipMemsetAsync(agg, 0, (size_t)N * DD * 4, stream);
        edge_scatter_k<<<(E + 3) / 4, 256, 0, stream>>>(
            hWn, rW, esrc, edst, erel, agg, E);
        finalize_k<<<(N * DD / 4 + 255) / 256, 256, 0, stream>>>(
            agg, loopm, norm, out, N);
        hin = out;
    }
}

// Round 2
// 375.742 us; speedup vs baseline: 2.8672x; 2.8672x over previous
//
#include <hip/hip_runtime.h>

#define DD 128
static constexpr float SLOPE = (1.0f/8.0f + 1.0f/3.0f) * 0.5f;  // rrelu eval slope

// ---------------- CSR build ----------------

__global__ __launch_bounds__(256) void hist_k(const int* __restrict__ dst,
                                              int* __restrict__ counts, int E) {
    int i = blockIdx.x * 256 + threadIdx.x;
    if (i < E) atomicAdd(&counts[dst[i]], 1);
}

#define SCAN_BS 256
#define SCAN_ELEMS 1024

__global__ __launch_bounds__(SCAN_BS) void block_reduce_k(const int* __restrict__ counts,
                                                          int* __restrict__ bsums, int N) {
    __shared__ int sm[SCAN_BS];
    int base = blockIdx.x * SCAN_ELEMS;
    int s = 0;
    for (int j = 0; j < 4; j++) {
        int idx = base + j * SCAN_BS + threadIdx.x;
        if (idx < N) s += counts[idx];
    }
    sm[threadIdx.x] = s; __syncthreads();
    for (int off = SCAN_BS / 2; off > 0; off >>= 1) {
        if (threadIdx.x < off) sm[threadIdx.x] += sm[threadIdx.x + off];
        __syncthreads();
    }
    if (threadIdx.x == 0) bsums[blockIdx.x] = sm[0];
}

// single block; nb <= 256
__global__ __launch_bounds__(SCAN_BS) void scan_bsums_k(int* __restrict__ bsums, int nb) {
    __shared__ int sm[SCAN_BS];
    int v = threadIdx.x < nb ? bsums[threadIdx.x] : 0;
    sm[threadIdx.x] = v; __syncthreads();
    for (int off = 1; off < SCAN_BS; off <<= 1) {
        int t = threadIdx.x >= off ? sm[threadIdx.x - off] : 0;
        __syncthreads();
        sm[threadIdx.x] += t;
        __syncthreads();
    }
    if (threadIdx.x < nb) bsums[threadIdx.x] = sm[threadIdx.x] - v;  // exclusive
}

__global__ __launch_bounds__(SCAN_BS) void scan_write_k(const int* __restrict__ counts,
                                                        const int* __restrict__ bsums,
                                                        int* __restrict__ pos, int N) {
    __shared__ int sm[SCAN_BS];
    int base = blockIdx.x * SCAN_ELEMS + threadIdx.x * 4;
    int c[4]; int s = 0;
    for (int j = 0; j < 4; j++) {
        int idx = base + j;
        c[j] = idx < N ? counts[idx] : 0;
        s += c[j];
    }
    sm[threadIdx.x] = s; __syncthreads();
    for (int off = 1; off < SCAN_BS; off <<= 1) {
        int t = threadIdx.x >= off ? sm[threadIdx.x - off] : 0;
        __syncthreads();
        sm[threadIdx.x] += t;
        __syncthreads();
    }
    int run = bsums[blockIdx.x] + sm[threadIdx.x] - s;  // exclusive offset
    for (int j = 0; j < 4; j++) {
        int idx = base + j;
        if (idx < N) pos[idx] = run;
        run += c[j];
    }
}

// pos[d] starts at exclusive offset; after this kernel pos[d] == segment end.
__global__ __launch_bounds__(256) void fill_k(const int* __restrict__ esrc,
                                              const int* __restrict__ edst,
                                              const int* __restrict__ erel,
                                              int* __restrict__ pos,
                                              int2* __restrict__ spack, int E) {
    int e = blockIdx.x * 256 + threadIdx.x;
    if (e >= E) return;
    int d = edst[e];
    int slot = atomicAdd(&pos[d], 1);
    spack[slot] = make_int2(esrc[e], erel[e]);
}

// ---------------- dense GEMM: out[r,:] = A[r,:] @ W ----------------
// Rows: r < N read from h, N <= r < M read from rel (may be null when M==N).
__global__ __launch_bounds__(256) void gemm128_k(
    const float* __restrict__ h, const float* __restrict__ rel,
    const float* __restrict__ W, float* __restrict__ out_h,
    float* __restrict__ out_rel, int N, int M)
{
    __shared__ float Ws[DD * DD];   // 64 KB
    __shared__ float As[32 * DD];   // 16 KB, per-row rotation swizzle
    int tid = threadIdx.x;

    for (int i = tid * 4; i < DD * DD; i += 256 * 4)
        *(float4*)&Ws[i] = *(const float4*)&W[i];

    int row0 = blockIdx.x * 32;
    for (int i = tid; i < 32 * DD / 4; i += 256) {
        int lr = i >> 5;
        int c4 = i & 31;
        int r = row0 + lr;
        float4 v = make_float4(0.f, 0.f, 0.f, 0.f);
        if (r < N)       v = *(const float4*)&h[(size_t)r * DD + c4 * 4];
        else if (r < M)  v = *(const float4*)&rel[(size_t)(r - N) * DD + c4 * 4];
        int c4s = (c4 + lr) & 31;
        *(float4*)&As[lr * DD + c4s * 4] = v;
    }
    __syncthreads();

    int lr = tid >> 3;
    int g  = tid & 7;
    float acc[16];
    #pragma unroll
    for (int j = 0; j < 16; j++) acc[j] = 0.f;

    #pragma unroll 4
    for (int k = 0; k < DD; k++) {
        float a = As[lr * DD + ((k + 4 * lr) & 127)];
        #pragma unroll
        for (int m = 0; m < 4; m++) {
            float4 w = *(const float4*)&Ws[k * DD + g * 4 + 32 * m];
            acc[m * 4 + 0] = fmaf(a, w.x, acc[m * 4 + 0]);
            acc[m * 4 + 1] = fmaf(a, w.y, acc[m * 4 + 1]);
            acc[m * 4 + 2] = fmaf(a, w.z, acc[m * 4 + 2]);
            acc[m * 4 + 3] = fmaf(a, w.w, acc[m * 4 + 3]);
        }
    }

    int r = row0 + lr;
    float* dstp;
    if (r < N)      dstp = out_h + (size_t)r * DD;
    else if (r < M) dstp = out_rel + (size_t)(r - N) * DD;
    else return;
    #pragma unroll
    for (int m = 0; m < 4; m++)
        *(float4*)&dstp[g * 4 + 32 * m] =
            make_float4(acc[m*4+0], acc[m*4+1], acc[m*4+2], acc[m*4+3]);
}

// Rows with indeg==0 (~2 of 50000) use W_evolve instead of W_loop.
__global__ void loop_fixup_k(const float* __restrict__ h, const float* __restrict__ We,
                             const int* __restrict__ counts, float* __restrict__ loopm,
                             int N) {
    int r = blockIdx.x;
    if (r >= N || counts[r] != 0) return;
    int c = threadIdx.x;  // 128 threads
    float acc = 0.f;
    for (int k = 0; k < DD; k++)
        acc = fmaf(h[(size_t)r * DD + k], We[k * DD + c], acc);
    loopm[(size_t)r * DD + c] = acc;
}

// ---------------- gather-side aggregate + fused finalize ----------------
// One wave (64 lanes) per dst node; lane covers 2 floats of the 128-d row.
__global__ __launch_bounds__(256) void aggregate_k(
    const float* __restrict__ hWn, const float* __restrict__ rW,
    const int2* __restrict__ spack,
    const int* __restrict__ endp, const int* __restrict__ counts,
    const float* __restrict__ loopm, const float* __restrict__ norm,
    float* __restrict__ hout, int N)
{
    int t = blockIdx.x * 256 + threadIdx.x;
    int r = t >> 6;
    if (r >= N) return;
    int lane = t & 63;
    int end = endp[r];
    int beg = end - counts[r];

    float2 acc = make_float2(0.f, 0.f);
    int i = beg;
    for (; i + 2 <= end; i += 2) {
        int2 p0 = spack[i];
        int2 p1 = spack[i + 1];
        float2 a0 = *(const float2*)&hWn[(size_t)p0.x * DD + lane * 2];
        float2 b0 = *(const float2*)&rW [(size_t)p0.y * DD + lane * 2];
        float2 a1 = *(const float2*)&hWn[(size_t)p1.x * DD + lane * 2];
        float2 b1 = *(const float2*)&rW [(size_t)p1.y * DD + lane * 2];
        acc.x += (a0.x + b0.x) + (a1.x + b1.x);
        acc.y += (a0.y + b0.y) + (a1.y + b1.y);
    }
    if (i < end) {
        int2 p0 = spack[i];
        float2 a0 = *(const float2*)&hWn[(size_t)p0.x * DD + lane * 2];
        float2 b0 = *(const float2*)&rW [(size_t)p0.y * DD + lane * 2];
        acc.x += a0.x + b0.x;
        acc.y += a0.y + b0.y;
    }

    float nv = norm[r];
    float2 lv = *(const float2*)&loopm[(size_t)r * DD + lane * 2];
    float2 o;
    o.x = acc.x * nv + lv.x;
    o.y = acc.y * nv + lv.y;
    o.x = o.x >= 0.f ? o.x : SLOPE * o.x;
    o.y = o.y >= 0.f ? o.y : SLOPE * o.y;
    *(float2*)&hout[(size_t)r * DD + lane * 2] = o;
}

extern "C" void kernel_launch(void* const* d_in, const int* in_sizes, int n_in,
                              void* d_out, int out_size, void* d_ws, size_t ws_size,
                              hipStream_t stream) {
    const float* node    = (const float*)d_in[0];
    const float* rel_emb = (const float*)d_in[1];
    const float* norm    = (const float*)d_in[2];
    const int*   esrc    = (const int*)d_in[3];
    const int*   edst    = (const int*)d_in[4];
    const int*   erel    = (const int*)d_in[5];
    const float* Wn      = (const float*)d_in[6];
    const float* Wl      = (const float*)d_in[7];
    const float* We      = (const float*)d_in[8];
    int N = in_sizes[0] / DD;
    int R = in_sizes[1] / DD;
    int E = in_sizes[3];
    float* out = (float*)d_out;

    char* w = (char*)d_ws;
    auto alloc = [&](size_t bytes) {
        void* p = (void*)w;
        w += (bytes + 255) & ~(size_t)255;
        return p;
    };
    int*   counts = (int*)  alloc((size_t)N * 4);
    int*   pos    = (int*)  alloc((size_t)N * 4);
    int*   bsums  = (int*)  alloc(4096);
    int2*  spack  = (int2*) alloc((size_t)E * 8);
    float* rW     = (float*)alloc((size_t)R * DD * 4);
    float* hWn    = (float*)alloc((size_t)N * DD * 4);
    float* loopm  = (float*)alloc((size_t)N * DD * 4);

    int nb = (N + SCAN_ELEMS - 1) / SCAN_ELEMS;  // 49 for N=50000

    // CSR build (once; reused by both layers)
    hipMemsetAsync(counts, 0, (size_t)N * 4, stream);
    hist_k<<<(E + 255) / 256, 256, 0, stream>>>(edst, counts, E);
    block_reduce_k<<<nb, SCAN_BS, 0, stream>>>(counts, bsums, N);
    scan_bsums_k<<<1, SCAN_BS, 0, stream>>>(bsums, nb);
    scan_write_k<<<nb, SCAN_BS, 0, stream>>>(counts, bsums, pos, N);
    fill_k<<<(E + 255) / 256, 256, 0, stream>>>(esrc, edst, erel, pos, spack, E);
    // after fill_k: pos[r] == segment end, counts[r] == segment length

    const float* hin = node;
    for (int l = 0; l < 2; l++) {
        int M = N + R;
        gemm128_k<<<(M + 31) / 32, 256, 0, stream>>>(
            hin, rel_emb, Wn + (size_t)l * DD * DD, hWn, rW, N, M);
        gemm128_k<<<(N + 31) / 32, 256, 0, stream>>>(
            hin, nullptr, Wl + (size_t)l * DD * DD, loopm, nullptr, N, N);
        loop_fixup_k<<<N, DD, 0, stream>>>(
            hin, We + (size_t)l * DD * DD, counts, loopm, N);
        aggregate_k<<<(N * 64 + 255) / 256, 256, 0, stream>>>(
            hWn, rW, spack, pos, counts, loopm, norm, out, N);
        hin = out;
    }
}

// Round 3
// 219.834 us; speedup vs baseline: 4.9007x; 1.7092x over previous
//
#include <hip/hip_runtime.h>

#define DD 128
static constexpr float SLOPE = (1.0f/8.0f + 1.0f/3.0f) * 0.5f;  // rrelu eval slope

typedef __attribute__((ext_vector_type(8))) short bf16x8;
typedef __attribute__((ext_vector_type(4))) float f32x4;

__device__ inline unsigned short f2bf(float x) {
    unsigned u = __builtin_bit_cast(unsigned, x);
    unsigned r = (u + 0x7FFFu + ((u >> 16) & 1u)) >> 16;
    return (unsigned short)r;
}
__device__ inline float bflo(unsigned u) {  // low bf16 -> f32
    unsigned v = u << 16; return __builtin_bit_cast(float, v);
}
__device__ inline float bfhi(unsigned u) {  // high bf16 -> f32
    unsigned v = u & 0xFFFF0000u; return __builtin_bit_cast(float, v);
}

// ---------------- CSR build ----------------

__global__ __launch_bounds__(256) void hist_k(const int* __restrict__ dst,
                                              int* __restrict__ counts, int E) {
    int i = blockIdx.x * 256 + threadIdx.x;
    if (i < E) atomicAdd(&counts[dst[i]], 1);
}

#define SCAN_BS 256
#define SCAN_ELEMS 1024

__global__ __launch_bounds__(SCAN_BS) void block_reduce_k(const int* __restrict__ counts,
                                                          int* __restrict__ bsums, int N) {
    __shared__ int sm[SCAN_BS];
    int base = blockIdx.x * SCAN_ELEMS;
    int s = 0;
    for (int j = 0; j < 4; j++) {
        int idx = base + j * SCAN_BS + threadIdx.x;
        if (idx < N) s += counts[idx];
    }
    sm[threadIdx.x] = s; __syncthreads();
    for (int off = SCAN_BS / 2; off > 0; off >>= 1) {
        if (threadIdx.x < off) sm[threadIdx.x] += sm[threadIdx.x + off];
        __syncthreads();
    }
    if (threadIdx.x == 0) bsums[blockIdx.x] = sm[0];
}

__global__ __launch_bounds__(SCAN_BS) void scan_bsums_k(int* __restrict__ bsums, int nb) {
    __shared__ int sm[SCAN_BS];
    int v = threadIdx.x < nb ? bsums[threadIdx.x] : 0;
    sm[threadIdx.x] = v; __syncthreads();
    for (int off = 1; off < SCAN_BS; off <<= 1) {
        int t = threadIdx.x >= off ? sm[threadIdx.x - off] : 0;
        __syncthreads();
        sm[threadIdx.x] += t;
        __syncthreads();
    }
    if (threadIdx.x < nb) bsums[threadIdx.x] = sm[threadIdx.x] - v;  // exclusive
}

__global__ __launch_bounds__(SCAN_BS) void scan_write_k(const int* __restrict__ counts,
                                                        const int* __restrict__ bsums,
                                                        int* __restrict__ pos, int N) {
    __shared__ int sm[SCAN_BS];
    int base = blockIdx.x * SCAN_ELEMS + threadIdx.x * 4;
    int c[4]; int s = 0;
    for (int j = 0; j < 4; j++) {
        int idx = base + j;
        c[j] = idx < N ? counts[idx] : 0;
        s += c[j];
    }
    sm[threadIdx.x] = s; __syncthreads();
    for (int off = 1; off < SCAN_BS; off <<= 1) {
        int t = threadIdx.x >= off ? sm[threadIdx.x - off] : 0;
        __syncthreads();
        sm[threadIdx.x] += t;
        __syncthreads();
    }
    int run = bsums[blockIdx.x] + sm[threadIdx.x] - s;  // exclusive offset
    for (int j = 0; j < 4; j++) {
        int idx = base + j;
        if (idx < N) pos[idx] = run;
        run += c[j];
    }
}

__global__ __launch_bounds__(256) void fill_k(const int* __restrict__ esrc,
                                              const int* __restrict__ edst,
                                              const int* __restrict__ erel,
                                              int* __restrict__ pos,
                                              int2* __restrict__ spack, int E) {
    int e = blockIdx.x * 256 + threadIdx.x;
    if (e >= E) return;
    int d = edst[e];
    int slot = atomicAdd(&pos[d], 1);
    spack[slot] = make_int2(esrc[e], erel[e]);
}

// ---------------- W pre-transpose: Wt[l][n][k] bf16, n<128 -> Wn, else Wl ----
__global__ __launch_bounds__(256) void wt_build_k(
    const float* __restrict__ Wn, const float* __restrict__ Wl,
    unsigned short* __restrict__ Wt)
{
    int i = blockIdx.x * 256 + threadIdx.x;   // 0..16383, 4 k-elems each
    int l = i >> 13;
    int rem = i & 8191;
    int n = rem >> 5;
    int k0 = (rem & 31) * 4;
    const float* src = (n < 128) ? (Wn + l * DD * DD + n)
                                 : (Wl + l * DD * DD + (n - 128));
    unsigned short o0 = f2bf(src[(k0 + 0) * DD]);
    unsigned short o1 = f2bf(src[(k0 + 1) * DD]);
    unsigned short o2 = f2bf(src[(k0 + 2) * DD]);
    unsigned short o3 = f2bf(src[(k0 + 3) * DD]);
    *(ushort4*)&Wt[((size_t)l * 256 + n) * DD + k0] = make_ushort4(o0, o1, o2, o3);
}

// ---------------- MFMA dual GEMM: [h;rel] @ [Wn | Wl] -> (hWn|loopm), rW ----
// BM=64 rows/block, BN=256 cols (128 Wn + 128 Wl), 4 waves (64 cols each).
__global__ __launch_bounds__(256) void gemm_dual_mfma_k(
    const float* __restrict__ h, const float* __restrict__ rel,
    const unsigned short* __restrict__ Wt,   // [256][128] bf16, this layer
    unsigned short* __restrict__ hWn,        // [N][128] bf16
    unsigned short* __restrict__ loopm,      // [N][128] bf16
    unsigned short* __restrict__ rW,         // [R][128] bf16
    int N, int R)
{
    __shared__ unsigned short Asm[64 * DD];    // 16 KB, XOR-swizzled rows
    __shared__ unsigned short Wsm[256 * DD];   // 64 KB, XOR-swizzled rows
    int tid = threadIdx.x;
    int row0 = blockIdx.x * 64;

    // stage Wt (bf16, already [n][k]): linear global read, swizzled LDS write
    #pragma unroll
    for (int it = 0; it < 16; ++it) {
        int ci = it * 256 + tid;                 // 16B chunk index 0..4095
        uint4 wv = *(const uint4*)((const char*)Wt + (size_t)ci * 16);
        int lin = ci * 16;
        int row = lin >> 8;
        int off = lin ^ ((row & 7) << 4);
        *(uint4*)((char*)Wsm + off) = wv;
    }

    // stage A (fp32 -> bf16), rows: [0,N) from h, [N,N+R) from rel, else 0
    {
        int r = tid >> 2, quad = tid & 3;        // 32 floats per thread
        int grow = row0 + r;
        const float* src = nullptr;
        if (grow < N)            src = h + (size_t)grow * DD + quad * 32;
        else if (grow - N < R)   src = rel + (size_t)(grow - N) * DD + quad * 32;
        int sw = (r & 7) << 4;
        #pragma unroll
        for (int c = 0; c < 4; ++c) {
            float4 v0 = make_float4(0.f, 0.f, 0.f, 0.f), v1 = v0;
            if (src) {
                v0 = *(const float4*)(src + c * 8);
                v1 = *(const float4*)(src + c * 8 + 4);
            }
            union { bf16x8 v; unsigned short u[8]; } pk;
            pk.u[0] = f2bf(v0.x); pk.u[1] = f2bf(v0.y);
            pk.u[2] = f2bf(v0.z); pk.u[3] = f2bf(v0.w);
            pk.u[4] = f2bf(v1.x); pk.u[5] = f2bf(v1.y);
            pk.u[6] = f2bf(v1.z); pk.u[7] = f2bf(v1.w);
            int off = r * 256 + ((quad * 64 + c * 16) ^ sw);
            *(bf16x8*)((char*)Asm + off) = pk.v;
        }
    }
    __syncthreads();

    int w = tid >> 6, lane = tid & 63;
    int g = lane >> 4, q = lane & 15;
    int sw = (q & 7) << 4;

    f32x4 acc[4][4];
    #pragma unroll
    for (int mi = 0; mi < 4; ++mi)
        #pragma unroll
        for (int ni = 0; ni < 4; ++ni)
            acc[mi][ni] = (f32x4){0.f, 0.f, 0.f, 0.f};

    #pragma unroll
    for (int s = 0; s < 4; ++s) {               // k = 32s .. 32s+31
        int off = 64 * s + 16 * g;              // byte offset within row
        bf16x8 a[4], b[4];
        #pragma unroll
        for (int mi = 0; mi < 4; ++mi) {
            int row = mi * 16 + q;
            a[mi] = *(const bf16x8*)((const char*)Asm + row * 256 + (off ^ sw));
        }
        #pragma unroll
        for (int ni = 0; ni < 4; ++ni) {
            int n = w * 64 + ni * 16 + q;
            b[ni] = *(const bf16x8*)((const char*)Wsm + n * 256 + (off ^ sw));
        }
        #pragma unroll
        for (int mi = 0; mi < 4; ++mi)
            #pragma unroll
            for (int ni = 0; ni < 4; ++ni)
                acc[mi][ni] = __builtin_amdgcn_mfma_f32_16x16x32_bf16(
                    a[mi], b[ni], acc[mi][ni], 0, 0, 0);
    }

    // epilogue: C/D layout col=lane&15, row=(lane>>4)*4+reg  [m89]
    #pragma unroll
    for (int mi = 0; mi < 4; ++mi) {
        int grow_base = row0 + mi * 16 + g * 4;
        #pragma unroll
        for (int ni = 0; ni < 4; ++ni) {
            int gcol = w * 64 + ni * 16 + q;    // 0..255
            #pragma unroll
            for (int j = 0; j < 4; ++j) {
                int grow = grow_base + j;
                unsigned short bv = f2bf(acc[mi][ni][j]);
                if (grow < N) {
                    if (gcol < DD) hWn[(size_t)grow * DD + gcol] = bv;
                    else           loopm[(size_t)grow * DD + gcol - DD] = bv;
                } else if (grow - N < R && gcol < DD) {
                    rW[(size_t)(grow - N) * DD + gcol] = bv;
                }
            }
        }
    }
}

// Rows with indeg==0 use W_evolve instead of W_loop (~e^-10 fraction).
__global__ void loop_fixup_k(const float* __restrict__ h, const float* __restrict__ We,
                             const int* __restrict__ counts,
                             unsigned short* __restrict__ loopm, int N) {
    int r = blockIdx.x;
    if (counts[r] != 0) return;
    int c = threadIdx.x;  // 128 threads
    float acc = 0.f;
    for (int k = 0; k < DD; k++)
        acc = fmaf(h[(size_t)r * DD + k], We[k * DD + c], acc);
    loopm[(size_t)r * DD + c] = f2bf(acc);
}

// ---------------- gather aggregate (bf16 in, fp32 accumulate) + finalize ----
__global__ __launch_bounds__(256) void aggregate_k(
    const unsigned short* __restrict__ hWn, const unsigned short* __restrict__ rW,
    const int2* __restrict__ spack,
    const int* __restrict__ endp, const int* __restrict__ counts,
    const unsigned short* __restrict__ loopm, const float* __restrict__ norm,
    float* __restrict__ hout, int N)
{
    int t = blockIdx.x * 256 + threadIdx.x;
    int r = t >> 6;
    if (r >= N) return;
    int lane = t & 63;
    int end = endp[r];
    int beg = end - counts[r];

    float ax = 0.f, ay = 0.f;
    int i = beg;
    for (; i + 2 <= end; i += 2) {
        int2 p0 = spack[i];
        int2 p1 = spack[i + 1];
        unsigned a0 = *(const unsigned*)&hWn[(size_t)p0.x * DD + lane * 2];
        unsigned b0 = *(const unsigned*)&rW [(size_t)p0.y * DD + lane * 2];
        unsigned a1 = *(const unsigned*)&hWn[(size_t)p1.x * DD + lane * 2];
        unsigned b1 = *(const unsigned*)&rW [(size_t)p1.y * DD + lane * 2];
        ax += (bflo(a0) + bflo(b0)) + (bflo(a1) + bflo(b1));
        ay += (bfhi(a0) + bfhi(b0)) + (bfhi(a1) + bfhi(b1));
    }
    if (i < end) {
        int2 p0 = spack[i];
        unsigned a0 = *(const unsigned*)&hWn[(size_t)p0.x * DD + lane * 2];
        unsigned b0 = *(const unsigned*)&rW [(size_t)p0.y * DD + lane * 2];
        ax += bflo(a0) + bflo(b0);
        ay += bfhi(a0) + bfhi(b0);
    }

    float nv = norm[r];
    unsigned lu = *(const unsigned*)&loopm[(size_t)r * DD + lane * 2];
    float ox = ax * nv + bflo(lu);
    float oy = ay * nv + bfhi(lu);
    ox = ox >= 0.f ? ox : SLOPE * ox;
    oy = oy >= 0.f ? oy : SLOPE * oy;
    *(float2*)&hout[(size_t)r * DD + lane * 2] = make_float2(ox, oy);
}

extern "C" void kernel_launch(void* const* d_in, const int* in_sizes, int n_in,
                              void* d_out, int out_size, void* d_ws, size_t ws_size,
                              hipStream_t stream) {
    const float* node    = (const float*)d_in[0];
    const float* rel_emb = (const float*)d_in[1];
    const float* norm    = (const float*)d_in[2];
    const int*   esrc    = (const int*)d_in[3];
    const int*   edst    = (const int*)d_in[4];
    const int*   erel    = (const int*)d_in[5];
    const float* Wn      = (const float*)d_in[6];
    const float* Wl      = (const float*)d_in[7];
    const float* We      = (const float*)d_in[8];
    int N = in_sizes[0] / DD;
    int R = in_sizes[1] / DD;
    int E = in_sizes[3];
    float* out = (float*)d_out;

    char* w = (char*)d_ws;
    auto alloc = [&](size_t bytes) {
        void* p = (void*)w;
        w += (bytes + 255) & ~(size_t)255;
        return p;
    };
    int*            counts = (int*)           alloc((size_t)N * 4);
    int*            pos    = (int*)           alloc((size_t)N * 4);
    int*            bsums  = (int*)           alloc(4096);
    int2*           spack  = (int2*)          alloc((size_t)E * 8);
    unsigned short* Wt     = (unsigned short*)alloc((size_t)2 * 256 * DD * 2);
    unsigned short* rW     = (unsigned short*)alloc((size_t)R * DD * 2);
    unsigned short* hWn    = (unsigned short*)alloc((size_t)N * DD * 2);
    unsigned short* loopm  = (unsigned short*)alloc((size_t)N * DD * 2);

    int nb = (N + SCAN_ELEMS - 1) / SCAN_ELEMS;

    // CSR build (reused by both layers)
    hipMemsetAsync(counts, 0, (size_t)N * 4, stream);
    wt_build_k<<<64, 256, 0, stream>>>(Wn, Wl, Wt);
    hist_k<<<(E + 255) / 256, 256, 0, stream>>>(edst, counts, E);
    block_reduce_k<<<nb, SCAN_BS, 0, stream>>>(counts, bsums, N);
    scan_bsums_k<<<1, SCAN_BS, 0, stream>>>(bsums, nb);
    scan_write_k<<<nb, SCAN_BS, 0, stream>>>(counts, bsums, pos, N);
    fill_k<<<(E + 255) / 256, 256, 0, stream>>>(esrc, edst, erel, pos, spack, E);
    // after fill_k: pos[r] == segment end, counts[r] == segment length

    const float* hin = node;
    int gemm_blocks = (N + R + 63) / 64;
    for (int l = 0; l < 2; l++) {
        gemm_dual_mfma_k<<<gemm_blocks, 256, 0, stream>>>(
            hin, rel_emb, Wt + (size_t)l * 256 * DD, hWn, loopm, rW, N, R);
        loop_fixup_k<<<N, DD, 0, stream>>>(
            hin, We + (size_t)l * DD * DD, counts, loopm, N);
        aggregate_k<<<(N * 64 + 255) / 256, 256, 0, stream>>>(
            hWn, rW, spack, pos, counts, loopm, norm, out, N);
        hin = out;
    }
}

// Round 4
// 182.394 us; speedup vs baseline: 5.9066x; 1.2053x over previous
//
#include <hip/hip_runtime.h>

#define DD 128
static constexpr float SLOPE = (1.0f/8.0f + 1.0f/3.0f) * 0.5f;  // rrelu eval slope

typedef __attribute__((ext_vector_type(8))) short bf16x8;
typedef __attribute__((ext_vector_type(4))) float f32x4;

__device__ inline unsigned short f2bf(float x) {
    unsigned u = __builtin_bit_cast(unsigned, x);
    unsigned r = (u + 0x7FFFu + ((u >> 16) & 1u)) >> 16;
    return (unsigned short)r;
}
__device__ inline float bflo(unsigned u) {  // low bf16 -> f32
    unsigned v = u << 16; return __builtin_bit_cast(float, v);
}
__device__ inline float bfhi(unsigned u) {  // high bf16 -> f32
    unsigned v = u & 0xFFFF0000u; return __builtin_bit_cast(float, v);
}

// ---------------- utility ----------------

__global__ __launch_bounds__(256) void zero_k(int* __restrict__ counts,
                                              int* __restrict__ nz, int N) {
    int i = blockIdx.x * 256 + threadIdx.x;
    if (i < N) counts[i] = 0;
    if (i == 0) *nz = 0;
}

// ---------------- CSR build ----------------

__global__ __launch_bounds__(256) void hist_k(const int* __restrict__ dst,
                                              int* __restrict__ counts, int E) {
    int i = blockIdx.x * 256 + threadIdx.x;
    if (i < E) atomicAdd(&counts[dst[i]], 1);
}

__global__ __launch_bounds__(256) void zlist_k(const int* __restrict__ counts,
                                               int* __restrict__ zlist,
                                               int* __restrict__ nz, int N) {
    int r = blockIdx.x * 256 + threadIdx.x;
    if (r < N && counts[r] == 0) {
        int i = atomicAdd(nz, 1);
        zlist[i] = r;
    }
}

#define SCAN_BS 256
#define SCAN_ELEMS 1024

__global__ __launch_bounds__(SCAN_BS) void block_reduce_k(const int* __restrict__ counts,
                                                          int* __restrict__ bsums, int N) {
    __shared__ int sm[SCAN_BS];
    int base = blockIdx.x * SCAN_ELEMS;
    int s = 0;
    for (int j = 0; j < 4; j++) {
        int idx = base + j * SCAN_BS + threadIdx.x;
        if (idx < N) s += counts[idx];
    }
    sm[threadIdx.x] = s; __syncthreads();
    for (int off = SCAN_BS / 2; off > 0; off >>= 1) {
        if (threadIdx.x < off) sm[threadIdx.x] += sm[threadIdx.x + off];
        __syncthreads();
    }
    if (threadIdx.x == 0) bsums[blockIdx.x] = sm[0];
}

__global__ __launch_bounds__(SCAN_BS) void scan_bsums_k(int* __restrict__ bsums, int nb) {
    __shared__ int sm[SCAN_BS];
    int v = threadIdx.x < nb ? bsums[threadIdx.x] : 0;
    sm[threadIdx.x] = v; __syncthreads();
    for (int off = 1; off < SCAN_BS; off <<= 1) {
        int t = threadIdx.x >= off ? sm[threadIdx.x - off] : 0;
        __syncthreads();
        sm[threadIdx.x] += t;
        __syncthreads();
    }
    if (threadIdx.x < nb) bsums[threadIdx.x] = sm[threadIdx.x] - v;  // exclusive
}

__global__ __launch_bounds__(SCAN_BS) void scan_write_k(const int* __restrict__ counts,
                                                        const int* __restrict__ bsums,
                                                        int* __restrict__ pos, int N) {
    __shared__ int sm[SCAN_BS];
    int base = blockIdx.x * SCAN_ELEMS + threadIdx.x * 4;
    int c[4]; int s = 0;
    for (int j = 0; j < 4; j++) {
        int idx = base + j;
        c[j] = idx < N ? counts[idx] : 0;
        s += c[j];
    }
    sm[threadIdx.x] = s; __syncthreads();
    for (int off = 1; off < SCAN_BS; off <<= 1) {
        int t = threadIdx.x >= off ? sm[threadIdx.x - off] : 0;
        __syncthreads();
        sm[threadIdx.x] += t;
        __syncthreads();
    }
    int run = bsums[blockIdx.x] + sm[threadIdx.x] - s;  // exclusive offset
    for (int j = 0; j < 4; j++) {
        int idx = base + j;
        if (idx < N) pos[idx] = run;
        run += c[j];
    }
}

__global__ __launch_bounds__(256) void fill_k(const int* __restrict__ esrc,
                                              const int* __restrict__ edst,
                                              const int* __restrict__ erel,
                                              int* __restrict__ pos,
                                              int2* __restrict__ spack, int E) {
    int e = blockIdx.x * 256 + threadIdx.x;
    if (e >= E) return;
    int d = edst[e];
    int slot = atomicAdd(&pos[d], 1);
    spack[slot] = make_int2(esrc[e], erel[e]);
}

// ---------------- W pre-transpose: Wt[l][n][k] bf16, n<128 -> Wn, else Wl ----
__global__ __launch_bounds__(256) void wt_build_k(
    const float* __restrict__ Wn, const float* __restrict__ Wl,
    unsigned short* __restrict__ Wt)
{
    int i = blockIdx.x * 256 + threadIdx.x;   // 0..16383, 4 k-elems each
    int l = i >> 13;
    int rem = i & 8191;
    int n = rem >> 5;
    int k0 = (rem & 31) * 4;
    const float* src = (n < 128) ? (Wn + l * DD * DD + n)
                                 : (Wl + l * DD * DD + (n - 128));
    unsigned short o0 = f2bf(src[(k0 + 0) * DD]);
    unsigned short o1 = f2bf(src[(k0 + 1) * DD]);
    unsigned short o2 = f2bf(src[(k0 + 2) * DD]);
    unsigned short o3 = f2bf(src[(k0 + 3) * DD]);
    *(ushort4*)&Wt[((size_t)l * 256 + n) * DD + k0] = make_ushort4(o0, o1, o2, o3);
}

// ---------------- MFMA dual GEMM: [h;rel] @ [Wn | Wl] -> (hWn|loopm), rW ----
// BM=64 rows/block, BN=256 cols (128 Wn + 128 Wl), 4 waves (64 cols each).
__global__ __launch_bounds__(256) void gemm_dual_mfma_k(
    const float* __restrict__ h, const float* __restrict__ rel,
    const unsigned short* __restrict__ Wt,   // [256][128] bf16, this layer
    unsigned short* __restrict__ hWn,        // [N][128] bf16
    unsigned short* __restrict__ loopm,      // [N][128] bf16
    unsigned short* __restrict__ rW,         // [R][128] bf16
    int N, int R)
{
    __shared__ unsigned short Asm[64 * DD];    // 16 KB, XOR-swizzled rows
    __shared__ unsigned short Wsm[256 * DD];   // 64 KB, XOR-swizzled rows
    int tid = threadIdx.x;
    int row0 = blockIdx.x * 64;

    // stage Wt (bf16, already [n][k]): linear global read, swizzled LDS write
    #pragma unroll
    for (int it = 0; it < 16; ++it) {
        int ci = it * 256 + tid;                 // 16B chunk index 0..4095
        uint4 wv = *(const uint4*)((const char*)Wt + (size_t)ci * 16);
        int lin = ci * 16;
        int row = lin >> 8;
        int off = lin ^ ((row & 7) << 4);
        *(uint4*)((char*)Wsm + off) = wv;
    }

    // stage A (fp32 -> bf16), rows: [0,N) from h, [N,N+R) from rel, else 0
    {
        int r = tid >> 2, quad = tid & 3;        // 32 floats per thread
        int grow = row0 + r;
        const float* src = nullptr;
        if (grow < N)            src = h + (size_t)grow * DD + quad * 32;
        else if (grow - N < R)   src = rel + (size_t)(grow - N) * DD + quad * 32;
        int sw = (r & 7) << 4;
        #pragma unroll
        for (int c = 0; c < 4; ++c) {
            float4 v0 = make_float4(0.f, 0.f, 0.f, 0.f), v1 = v0;
            if (src) {
                v0 = *(const float4*)(src + c * 8);
                v1 = *(const float4*)(src + c * 8 + 4);
            }
            union { bf16x8 v; unsigned short u[8]; } pk;
            pk.u[0] = f2bf(v0.x); pk.u[1] = f2bf(v0.y);
            pk.u[2] = f2bf(v0.z); pk.u[3] = f2bf(v0.w);
            pk.u[4] = f2bf(v1.x); pk.u[5] = f2bf(v1.y);
            pk.u[6] = f2bf(v1.z); pk.u[7] = f2bf(v1.w);
            int off = r * 256 + ((quad * 64 + c * 16) ^ sw);
            *(bf16x8*)((char*)Asm + off) = pk.v;
        }
    }
    __syncthreads();

    int w = tid >> 6, lane = tid & 63;
    int g = lane >> 4, q = lane & 15;
    int sw = (q & 7) << 4;

    f32x4 acc[4][4];
    #pragma unroll
    for (int mi = 0; mi < 4; ++mi)
        #pragma unroll
        for (int ni = 0; ni < 4; ++ni)
            acc[mi][ni] = (f32x4){0.f, 0.f, 0.f, 0.f};

    #pragma unroll
    for (int s = 0; s < 4; ++s) {               // k = 32s .. 32s+31
        int off = 64 * s + 16 * g;              // byte offset within row
        bf16x8 a[4], b[4];
        #pragma unroll
        for (int mi = 0; mi < 4; ++mi) {
            int row = mi * 16 + q;
            a[mi] = *(const bf16x8*)((const char*)Asm + row * 256 + (off ^ sw));
        }
        #pragma unroll
        for (int ni = 0; ni < 4; ++ni) {
            int n = w * 64 + ni * 16 + q;
            b[ni] = *(const bf16x8*)((const char*)Wsm + n * 256 + (off ^ sw));
        }
        #pragma unroll
        for (int mi = 0; mi < 4; ++mi)
            #pragma unroll
            for (int ni = 0; ni < 4; ++ni)
                acc[mi][ni] = __builtin_amdgcn_mfma_f32_16x16x32_bf16(
                    a[mi], b[ni], acc[mi][ni], 0, 0, 0);
    }

    // epilogue: C/D layout col=lane&15, row=(lane>>4)*4+reg  [m89]
    #pragma unroll
    for (int mi = 0; mi < 4; ++mi) {
        int grow_base = row0 + mi * 16 + g * 4;
        #pragma unroll
        for (int ni = 0; ni < 4; ++ni) {
            int gcol = w * 64 + ni * 16 + q;    // 0..255
            #pragma unroll
            for (int j = 0; j < 4; ++j) {
                int grow = grow_base + j;
                unsigned short bv = f2bf(acc[mi][ni][j]);
                if (grow < N) {
                    if (gcol < DD) hWn[(size_t)grow * DD + gcol] = bv;
                    else           loopm[(size_t)grow * DD + gcol - DD] = bv;
                } else if (grow - N < R && gcol < DD) {
                    rW[(size_t)(grow - N) * DD + gcol] = bv;
                }
            }
        }
    }
}

// Rows with indeg==0 use W_evolve instead of W_loop (~e^-10 fraction, ~2 rows).
// Fixed 64-block grid; list length read from device memory.
__global__ __launch_bounds__(128) void loop_fixup_k(
    const float* __restrict__ h, const float* __restrict__ We,
    const int* __restrict__ zlist, const int* __restrict__ nz,
    unsigned short* __restrict__ loopm)
{
    int n = *nz;
    int c = threadIdx.x;  // 128 threads
    for (int idx = blockIdx.x; idx < n; idx += gridDim.x) {
        int r = zlist[idx];
        float acc = 0.f;
        for (int k = 0; k < DD; k++)
            acc = fmaf(h[(size_t)r * DD + k], We[k * DD + c], acc);
        loopm[(size_t)r * DD + c] = f2bf(acc);
    }
}

// ---------------- gather aggregate (bf16 in, fp32 accumulate) + finalize ----
// 16 lanes per dst row (16B/lane dwordx4 gathers), 4 rows per wave.
__global__ __launch_bounds__(256) void aggregate_k(
    const unsigned short* __restrict__ hWn, const unsigned short* __restrict__ rW,
    const int2* __restrict__ spack,
    const int* __restrict__ endp, const int* __restrict__ counts,
    const unsigned short* __restrict__ loopm, const float* __restrict__ norm,
    float* __restrict__ hout, int N)
{
    int t = blockIdx.x * 256 + threadIdx.x;
    int r = t >> 4;              // 16 lanes per row
    if (r >= N) return;
    int sl = t & 15;             // sub-lane: bytes sl*16 of the 256B bf16 row
    int end = endp[r];
    int beg = end - counts[r];

    const char* hb = (const char*)hWn;
    const char* rb = (const char*)rW;
    size_t boff = (size_t)sl * 16;

    float acc[8];
    #pragma unroll
    for (int j = 0; j < 8; ++j) acc[j] = 0.f;

    int i = beg;
    for (; i + 2 <= end; i += 2) {
        int2 p0 = spack[i];
        int2 p1 = spack[i + 1];
        uint4 a0 = *(const uint4*)(hb + (size_t)p0.x * 256 + boff);
        uint4 b0 = *(const uint4*)(rb + (size_t)p0.y * 256 + boff);
        uint4 a1 = *(const uint4*)(hb + (size_t)p1.x * 256 + boff);
        uint4 b1 = *(const uint4*)(rb + (size_t)p1.y * 256 + boff);
        acc[0] += (bflo(a0.x) + bflo(b0.x)) + (bflo(a1.x) + bflo(b1.x));
        acc[1] += (bfhi(a0.x) + bfhi(b0.x)) + (bfhi(a1.x) + bfhi(b1.x));
        acc[2] += (bflo(a0.y) + bflo(b0.y)) + (bflo(a1.y) + bflo(b1.y));
        acc[3] += (bfhi(a0.y) + bfhi(b0.y)) + (bfhi(a1.y) + bfhi(b1.y));
        acc[4] += (bflo(a0.z) + bflo(b0.z)) + (bflo(a1.z) + bflo(b1.z));
        acc[5] += (bfhi(a0.z) + bfhi(b0.z)) + (bfhi(a1.z) + bfhi(b1.z));
        acc[6] += (bflo(a0.w) + bflo(b0.w)) + (bflo(a1.w) + bflo(b1.w));
        acc[7] += (bfhi(a0.w) + bfhi(b0.w)) + (bfhi(a1.w) + bfhi(b1.w));
    }
    if (i < end) {
        int2 p0 = spack[i];
        uint4 a0 = *(const uint4*)(hb + (size_t)p0.x * 256 + boff);
        uint4 b0 = *(const uint4*)(rb + (size_t)p0.y * 256 + boff);
        acc[0] += bflo(a0.x) + bflo(b0.x);
        acc[1] += bfhi(a0.x) + bfhi(b0.x);
        acc[2] += bflo(a0.y) + bflo(b0.y);
        acc[3] += bfhi(a0.y) + bfhi(b0.y);
        acc[4] += bflo(a0.z) + bflo(b0.z);
        acc[5] += bfhi(a0.z) + bfhi(b0.z);
        acc[6] += bflo(a0.w) + bflo(b0.w);
        acc[7] += bfhi(a0.w) + bfhi(b0.w);
    }

    float nv = norm[r];
    uint4 lu = *(const uint4*)((const char*)loopm + (size_t)r * 256 + boff);
    float o[8];
    o[0] = acc[0] * nv + bflo(lu.x);
    o[1] = acc[1] * nv + bfhi(lu.x);
    o[2] = acc[2] * nv + bflo(lu.y);
    o[3] = acc[3] * nv + bfhi(lu.y);
    o[4] = acc[4] * nv + bflo(lu.z);
    o[5] = acc[5] * nv + bfhi(lu.z);
    o[6] = acc[6] * nv + bflo(lu.w);
    o[7] = acc[7] * nv + bfhi(lu.w);
    #pragma unroll
    for (int j = 0; j < 8; ++j) o[j] = o[j] >= 0.f ? o[j] : SLOPE * o[j];

    float* op = &hout[(size_t)r * DD + sl * 8];
    *(float4*)op       = make_float4(o[0], o[1], o[2], o[3]);
    *(float4*)(op + 4) = make_float4(o[4], o[5], o[6], o[7]);
}

extern "C" void kernel_launch(void* const* d_in, const int* in_sizes, int n_in,
                              void* d_out, int out_size, void* d_ws, size_t ws_size,
                              hipStream_t stream) {
    const float* node    = (const float*)d_in[0];
    const float* rel_emb = (const float*)d_in[1];
    const float* norm    = (const float*)d_in[2];
    const int*   esrc    = (const int*)d_in[3];
    const int*   edst    = (const int*)d_in[4];
    const int*   erel    = (const int*)d_in[5];
    const float* Wn      = (const float*)d_in[6];
    const float* Wl      = (const float*)d_in[7];
    const float* We      = (const float*)d_in[8];
    int N = in_sizes[0] / DD;
    int R = in_sizes[1] / DD;
    int E = in_sizes[3];
    float* out = (float*)d_out;

    char* w = (char*)d_ws;
    auto alloc = [&](size_t bytes) {
        void* p = (void*)w;
        w += (bytes + 255) & ~(size_t)255;
        return p;
    };
    int*            counts = (int*)           alloc((size_t)N * 4);
    int*            pos    = (int*)           alloc((size_t)N * 4);
    int*            bsums  = (int*)           alloc(4096);
    int*            zlist  = (int*)           alloc((size_t)N * 4);
    int*            nz     = (int*)           alloc(256);
    int2*           spack  = (int2*)          alloc((size_t)E * 8);
    unsigned short* Wt     = (unsigned short*)alloc((size_t)2 * 256 * DD * 2);
    unsigned short* rW     = (unsigned short*)alloc((size_t)R * DD * 2);
    unsigned short* hWn    = (unsigned short*)alloc((size_t)N * DD * 2);
    unsigned short* loopm  = (unsigned short*)alloc((size_t)N * DD * 2);

    int nb = (N + SCAN_ELEMS - 1) / SCAN_ELEMS;

    // CSR build (reused by both layers)
    zero_k<<<(N + 255) / 256, 256, 0, stream>>>(counts, nz, N);
    wt_build_k<<<64, 256, 0, stream>>>(Wn, Wl, Wt);
    hist_k<<<(E + 255) / 256, 256, 0, stream>>>(edst, counts, E);
    zlist_k<<<(N + 255) / 256, 256, 0, stream>>>(counts, zlist, nz, N);
    block_reduce_k<<<nb, SCAN_BS, 0, stream>>>(counts, bsums, N);
    scan_bsums_k<<<1, SCAN_BS, 0, stream>>>(bsums, nb);
    scan_write_k<<<nb, SCAN_BS, 0, stream>>>(counts, bsums, pos, N);
    fill_k<<<(E + 255) / 256, 256, 0, stream>>>(esrc, edst, erel, pos, spack, E);
    // after fill_k: pos[r] == segment end, counts[r] == segment length

    const float* hin = node;
    int gemm_blocks = (N + R + 63) / 64;
    for (int l = 0; l < 2; l++) {
        gemm_dual_mfma_k<<<gemm_blocks, 256, 0, stream>>>(
            hin, rel_emb, Wt + (size_t)l * 256 * DD, hWn, loopm, rW, N, R);
        loop_fixup_k<<<64, 128, 0, stream>>>(
            hin, We + (size_t)l * DD * DD, zlist, nz, loopm);
        aggregate_k<<<(N * 16 + 255) / 256, 256, 0, stream>>>(
            hWn, rW, spack, pos, counts, loopm, norm, out, N);
        hin = out;
    }
}

// Round 5
// 166.263 us; speedup vs baseline: 6.4797x; 1.0970x over previous
//
#include <hip/hip_runtime.h>

#define DD 128
static constexpr float SLOPE = (1.0f/8.0f + 1.0f/3.0f) * 0.5f;  // rrelu eval slope

typedef __attribute__((ext_vector_type(8))) short bf16x8;
typedef __attribute__((ext_vector_type(4))) float f32x4;

__device__ inline unsigned short f2bf(float x) {
    unsigned u = __builtin_bit_cast(unsigned, x);
    unsigned r = (u + 0x7FFFu + ((u >> 16) & 1u)) >> 16;
    return (unsigned short)r;
}
__device__ inline float bflo(unsigned u) {  // low bf16 -> f32
    unsigned v = u << 16; return __builtin_bit_cast(float, v);
}
__device__ inline float bfhi(unsigned u) {  // high bf16 -> f32
    unsigned v = u & 0xFFFF0000u; return __builtin_bit_cast(float, v);
}

// ---- init: zero counts + build Wt[l][n][k] bf16 (n<128 -> Wn col, else Wl) ----
__global__ __launch_bounds__(256) void init_k(
    const float* __restrict__ Wn, const float* __restrict__ Wl,
    unsigned short* __restrict__ Wt, int* __restrict__ counts, int N)
{
    int b = blockIdx.x;
    if (b < 64) {
        int i = b * 256 + threadIdx.x;        // 0..16383, 4 k-elems each
        int l = i >> 13;
        int rem = i & 8191;
        int n = rem >> 5;
        int k0 = (rem & 31) * 4;
        const float* src = (n < 128) ? (Wn + l * DD * DD + n)
                                     : (Wl + l * DD * DD + (n - 128));
        unsigned short o0 = f2bf(src[(k0 + 0) * DD]);
        unsigned short o1 = f2bf(src[(k0 + 1) * DD]);
        unsigned short o2 = f2bf(src[(k0 + 2) * DD]);
        unsigned short o3 = f2bf(src[(k0 + 3) * DD]);
        *(ushort4*)&Wt[((size_t)l * 256 + n) * DD + k0] = make_ushort4(o0, o1, o2, o3);
    } else {
        int i = (b - 64) * 256 + threadIdx.x;
        if (i < N) counts[i] = 0;
    }
}

// ---------------- CSR build ----------------

__global__ __launch_bounds__(256) void hist_k(const int* __restrict__ dst,
                                              int* __restrict__ counts, int E) {
    int i = blockIdx.x * 256 + threadIdx.x;
    if (i < E) atomicAdd(&counts[dst[i]], 1);
}

#define SCAN_BS 256
#define SCAN_ELEMS 1024

__global__ __launch_bounds__(SCAN_BS) void block_reduce_k(const int* __restrict__ counts,
                                                          int* __restrict__ bsums, int N) {
    __shared__ int sm[SCAN_BS];
    int base = blockIdx.x * SCAN_ELEMS;
    int s = 0;
    for (int j = 0; j < 4; j++) {
        int idx = base + j * SCAN_BS + threadIdx.x;
        if (idx < N) s += counts[idx];
    }
    sm[threadIdx.x] = s; __syncthreads();
    for (int off = SCAN_BS / 2; off > 0; off >>= 1) {
        if (threadIdx.x < off) sm[threadIdx.x] += sm[threadIdx.x + off];
        __syncthreads();
    }
    if (threadIdx.x == 0) bsums[blockIdx.x] = sm[0];
}

__global__ __launch_bounds__(SCAN_BS) void scan_bsums_k(int* __restrict__ bsums, int nb) {
    __shared__ int sm[SCAN_BS];
    int v = threadIdx.x < nb ? bsums[threadIdx.x] : 0;
    sm[threadIdx.x] = v; __syncthreads();
    for (int off = 1; off < SCAN_BS; off <<= 1) {
        int t = threadIdx.x >= off ? sm[threadIdx.x - off] : 0;
        __syncthreads();
        sm[threadIdx.x] += t;
        __syncthreads();
    }
    if (threadIdx.x < nb) bsums[threadIdx.x] = sm[threadIdx.x] - v;  // exclusive
}

__global__ __launch_bounds__(SCAN_BS) void scan_write_k(const int* __restrict__ counts,
                                                        const int* __restrict__ bsums,
                                                        int* __restrict__ pos, int N) {
    __shared__ int sm[SCAN_BS];
    int base = blockIdx.x * SCAN_ELEMS + threadIdx.x * 4;
    int c[4]; int s = 0;
    for (int j = 0; j < 4; j++) {
        int idx = base + j;
        c[j] = idx < N ? counts[idx] : 0;
        s += c[j];
    }
    sm[threadIdx.x] = s; __syncthreads();
    for (int off = 1; off < SCAN_BS; off <<= 1) {
        int t = threadIdx.x >= off ? sm[threadIdx.x - off] : 0;
        __syncthreads();
        sm[threadIdx.x] += t;
        __syncthreads();
    }
    int run = bsums[blockIdx.x] + sm[threadIdx.x] - s;  // exclusive offset
    for (int j = 0; j < 4; j++) {
        int idx = base + j;
        if (idx < N) pos[idx] = run;
        run += c[j];
    }
}

// pack src | (rel<<17): src < 2^17, rel < 460 < 2^9
__global__ __launch_bounds__(256) void fill_k(const int* __restrict__ esrc,
                                              const int* __restrict__ edst,
                                              const int* __restrict__ erel,
                                              int* __restrict__ pos,
                                              int* __restrict__ spack, int E) {
    int e = blockIdx.x * 256 + threadIdx.x;
    if (e >= E) return;
    int d = edst[e];
    int slot = atomicAdd(&pos[d], 1);
    spack[slot] = esrc[e] | (erel[e] << 17);
}

// ---------------- MFMA dual GEMM: [h;rel] @ [Wn | Wl] -> (hWn|loopm), rW ----
// BM=64 rows/block, BN=256 cols, 4 waves (64 cols each). A rows [0,N) from
// hsrc (fp32 if !BF16IN else bf16), [N,N+R) from rel (fp32).
template<bool BF16IN>
__global__ __launch_bounds__(256) void gemm_dual_mfma_k(
    const void* __restrict__ hsrc, const float* __restrict__ rel,
    const unsigned short* __restrict__ Wt,   // [256][128] bf16, this layer
    unsigned short* __restrict__ hWn,        // [N][128] bf16
    unsigned short* __restrict__ loopm,      // [N][128] bf16
    unsigned short* __restrict__ rW,         // [R][128] bf16
    int N, int R)
{
    __shared__ unsigned short Asm[64 * DD];    // 16 KB, XOR-swizzled rows
    __shared__ unsigned short Wsm[256 * DD];   // 64 KB, XOR-swizzled rows
    int tid = threadIdx.x;
    int row0 = blockIdx.x * 64;

    // stage Wt (bf16, already [n][k]): linear global read, swizzled LDS write
    #pragma unroll
    for (int it = 0; it < 16; ++it) {
        int ci = it * 256 + tid;                 // 16B chunk index 0..4095
        uint4 wv = *(const uint4*)((const char*)Wt + (size_t)ci * 16);
        int lin = ci * 16;
        int row = lin >> 8;
        int off = lin ^ ((row & 7) << 4);
        *(uint4*)((char*)Wsm + off) = wv;
    }

    // stage A, rows: [0,N) from hsrc, [N,N+R) from rel, else 0
    {
        int rr = tid >> 2, quad = tid & 3;       // 32 elems per thread
        int grow = row0 + rr;
        int sw = (rr & 7) << 4;
        #pragma unroll
        for (int c = 0; c < 4; ++c) {
            bf16x8 pk = (bf16x8){0, 0, 0, 0, 0, 0, 0, 0};
            if (grow < N) {
                if constexpr (BF16IN) {
                    pk = *(const bf16x8*)((const unsigned short*)hsrc
                            + (size_t)grow * DD + quad * 32 + c * 8);
                } else {
                    const float* s = (const float*)hsrc + (size_t)grow * DD + quad * 32 + c * 8;
                    float4 v0 = *(const float4*)s;
                    float4 v1 = *(const float4*)(s + 4);
                    union { bf16x8 v; unsigned short u[8]; } t;
                    t.u[0] = f2bf(v0.x); t.u[1] = f2bf(v0.y);
                    t.u[2] = f2bf(v0.z); t.u[3] = f2bf(v0.w);
                    t.u[4] = f2bf(v1.x); t.u[5] = f2bf(v1.y);
                    t.u[6] = f2bf(v1.z); t.u[7] = f2bf(v1.w);
                    pk = t.v;
                }
            } else if (grow - N < R) {
                const float* s = rel + (size_t)(grow - N) * DD + quad * 32 + c * 8;
                float4 v0 = *(const float4*)s;
                float4 v1 = *(const float4*)(s + 4);
                union { bf16x8 v; unsigned short u[8]; } t;
                t.u[0] = f2bf(v0.x); t.u[1] = f2bf(v0.y);
                t.u[2] = f2bf(v0.z); t.u[3] = f2bf(v0.w);
                t.u[4] = f2bf(v1.x); t.u[5] = f2bf(v1.y);
                t.u[6] = f2bf(v1.z); t.u[7] = f2bf(v1.w);
                pk = t.v;
            }
            int off = rr * 256 + ((quad * 64 + c * 16) ^ sw);
            *(bf16x8*)((char*)Asm + off) = pk;
        }
    }
    __syncthreads();

    int w = tid >> 6, lane = tid & 63;
    int g = lane >> 4, q = lane & 15;
    int sw = (q & 7) << 4;

    f32x4 acc[4][4];
    #pragma unroll
    for (int mi = 0; mi < 4; ++mi)
        #pragma unroll
        for (int ni = 0; ni < 4; ++ni)
            acc[mi][ni] = (f32x4){0.f, 0.f, 0.f, 0.f};

    #pragma unroll
    for (int s = 0; s < 4; ++s) {               // k = 32s .. 32s+31
        int off = 64 * s + 16 * g;              // byte offset within row
        bf16x8 a[4], b[4];
        #pragma unroll
        for (int mi = 0; mi < 4; ++mi) {
            int row = mi * 16 + q;
            a[mi] = *(const bf16x8*)((const char*)Asm + row * 256 + (off ^ sw));
        }
        #pragma unroll
        for (int ni = 0; ni < 4; ++ni) {
            int n = w * 64 + ni * 16 + q;
            b[ni] = *(const bf16x8*)((const char*)Wsm + n * 256 + (off ^ sw));
        }
        #pragma unroll
        for (int mi = 0; mi < 4; ++mi)
            #pragma unroll
            for (int ni = 0; ni < 4; ++ni)
                acc[mi][ni] = __builtin_amdgcn_mfma_f32_16x16x32_bf16(
                    a[mi], b[ni], acc[mi][ni], 0, 0, 0);
    }

    // epilogue: C/D layout col=lane&15, row=(lane>>4)*4+reg  [m89]
    #pragma unroll
    for (int mi = 0; mi < 4; ++mi) {
        int grow_base = row0 + mi * 16 + g * 4;
        #pragma unroll
        for (int ni = 0; ni < 4; ++ni) {
            int gcol = w * 64 + ni * 16 + q;    // 0..255
            #pragma unroll
            for (int j = 0; j < 4; ++j) {
                int grow = grow_base + j;
                unsigned short bv = f2bf(acc[mi][ni][j]);
                if (grow < N) {
                    if (gcol < DD) hWn[(size_t)grow * DD + gcol] = bv;
                    else           loopm[(size_t)grow * DD + gcol - DD] = bv;
                } else if (grow - N < R && gcol < DD) {
                    rW[(size_t)(grow - N) * DD + gcol] = bv;
                }
            }
        }
    }
}

// ---------------- gather aggregate + fused finalize + fused evolve-fixup ----
// 16 lanes per dst row (16B/lane dwordx4 gathers), 4 rows per wave.
// count==0 rows (~e^-10 of N): o = rrelu(h_prev @ We) computed inline.
#define ACC8(A, B) do { \
    acc[0] += bflo((A).x) + bflo((B).x); acc[1] += bfhi((A).x) + bfhi((B).x); \
    acc[2] += bflo((A).y) + bflo((B).y); acc[3] += bfhi((A).y) + bfhi((B).y); \
    acc[4] += bflo((A).z) + bflo((B).z); acc[5] += bfhi((A).z) + bfhi((B).z); \
    acc[6] += bflo((A).w) + bflo((B).w); acc[7] += bfhi((A).w) + bfhi((B).w); \
} while (0)

template<bool LAYER1>
__global__ __launch_bounds__(256) void aggregate_k(
    const unsigned short* __restrict__ hWn, const unsigned short* __restrict__ rW,
    const int* __restrict__ spack,
    const int* __restrict__ endp, const int* __restrict__ counts,
    const unsigned short* __restrict__ loopm, const float* __restrict__ norm,
    const float* __restrict__ hf32,            // LAYER1: prev h (fp32)
    const unsigned short* __restrict__ hbf_in, // !LAYER1: prev h (bf16)
    const float* __restrict__ We,              // this layer's W_evolve
    unsigned short* __restrict__ hbf_out,      // LAYER1 output (bf16)
    float* __restrict__ fout,                  // !LAYER1 output (fp32)
    int N)
{
    int t = blockIdx.x * 256 + threadIdx.x;
    int r = t >> 4;              // 16 lanes per row
    if (r >= N) return;
    int sl = t & 15;             // sub-lane: bytes sl*16 of the 256B bf16 row
    int cnt = counts[r];
    int end = endp[r];
    size_t boff = (size_t)sl * 16;

    float o[8];
    if (cnt == 0) {
        // evolve self-loop: o[j] = sum_k h[r][k] * We[k][sl*8+j]
        #pragma unroll
        for (int j = 0; j < 8; ++j) o[j] = 0.f;
        for (int k = 0; k < DD; ++k) {
            float hk;
            if constexpr (LAYER1) hk = hf32[(size_t)r * DD + k];
            else                  hk = bflo((unsigned)hbf_in[(size_t)r * DD + k]);
            const float* wr = We + (size_t)k * DD + sl * 8;
            float4 w0 = *(const float4*)wr;
            float4 w1 = *(const float4*)(wr + 4);
            o[0] += hk * w0.x; o[1] += hk * w0.y;
            o[2] += hk * w0.z; o[3] += hk * w0.w;
            o[4] += hk * w1.x; o[5] += hk * w1.y;
            o[6] += hk * w1.z; o[7] += hk * w1.w;
        }
    } else {
        const char* hb = (const char*)hWn;
        const char* rb = (const char*)rW;
        int beg = end - cnt;
        float acc[8];
        #pragma unroll
        for (int j = 0; j < 8; ++j) acc[j] = 0.f;

        int i = beg;
        for (; i + 4 <= end; i += 4) {
            int p0 = spack[i], p1 = spack[i + 1], p2 = spack[i + 2], p3 = spack[i + 3];
            uint4 a0 = *(const uint4*)(hb + (size_t)(p0 & 0x1FFFF) * 256 + boff);
            uint4 b0 = *(const uint4*)(rb + (size_t)(p0 >> 17) * 256 + boff);
            uint4 a1 = *(const uint4*)(hb + (size_t)(p1 & 0x1FFFF) * 256 + boff);
            uint4 b1 = *(const uint4*)(rb + (size_t)(p1 >> 17) * 256 + boff);
            uint4 a2 = *(const uint4*)(hb + (size_t)(p2 & 0x1FFFF) * 256 + boff);
            uint4 b2 = *(const uint4*)(rb + (size_t)(p2 >> 17) * 256 + boff);
            uint4 a3 = *(const uint4*)(hb + (size_t)(p3 & 0x1FFFF) * 256 + boff);
            uint4 b3 = *(const uint4*)(rb + (size_t)(p3 >> 17) * 256 + boff);
            ACC8(a0, b0); ACC8(a1, b1); ACC8(a2, b2); ACC8(a3, b3);
        }
        for (; i + 2 <= end; i += 2) {
            int p0 = spack[i], p1 = spack[i + 1];
            uint4 a0 = *(const uint4*)(hb + (size_t)(p0 & 0x1FFFF) * 256 + boff);
            uint4 b0 = *(const uint4*)(rb + (size_t)(p0 >> 17) * 256 + boff);
            uint4 a1 = *(const uint4*)(hb + (size_t)(p1 & 0x1FFFF) * 256 + boff);
            uint4 b1 = *(const uint4*)(rb + (size_t)(p1 >> 17) * 256 + boff);
            ACC8(a0, b0); ACC8(a1, b1);
        }
        if (i < end) {
            int p0 = spack[i];
            uint4 a0 = *(const uint4*)(hb + (size_t)(p0 & 0x1FFFF) * 256 + boff);
            uint4 b0 = *(const uint4*)(rb + (size_t)(p0 >> 17) * 256 + boff);
            ACC8(a0, b0);
        }

        float nv = norm[r];
        uint4 lu = *(const uint4*)((const char*)loopm + (size_t)r * 256 + boff);
        o[0] = acc[0] * nv + bflo(lu.x);
        o[1] = acc[1] * nv + bfhi(lu.x);
        o[2] = acc[2] * nv + bflo(lu.y);
        o[3] = acc[3] * nv + bfhi(lu.y);
        o[4] = acc[4] * nv + bflo(lu.z);
        o[5] = acc[5] * nv + bfhi(lu.z);
        o[6] = acc[6] * nv + bflo(lu.w);
        o[7] = acc[7] * nv + bfhi(lu.w);
    }

    #pragma unroll
    for (int j = 0; j < 8; ++j) o[j] = o[j] >= 0.f ? o[j] : SLOPE * o[j];

    if constexpr (LAYER1) {
        union { bf16x8 v; unsigned short u[8]; } t;
        #pragma unroll
        for (int j = 0; j < 8; ++j) t.u[j] = f2bf(o[j]);
        *(bf16x8*)&hbf_out[(size_t)r * DD + sl * 8] = t.v;
    } else {
        float* op = &fout[(size_t)r * DD + sl * 8];
        *(float4*)op       = make_float4(o[0], o[1], o[2], o[3]);
        *(float4*)(op + 4) = make_float4(o[4], o[5], o[6], o[7]);
    }
}

extern "C" void kernel_launch(void* const* d_in, const int* in_sizes, int n_in,
                              void* d_out, int out_size, void* d_ws, size_t ws_size,
                              hipStream_t stream) {
    const float* node    = (const float*)d_in[0];
    const float* rel_emb = (const float*)d_in[1];
    const float* norm    = (const float*)d_in[2];
    const int*   esrc    = (const int*)d_in[3];
    const int*   edst    = (const int*)d_in[4];
    const int*   erel    = (const int*)d_in[5];
    const float* Wn      = (const float*)d_in[6];
    const float* Wl      = (const float*)d_in[7];
    const float* We      = (const float*)d_in[8];
    int N = in_sizes[0] / DD;
    int R = in_sizes[1] / DD;
    int E = in_sizes[3];
    float* out = (float*)d_out;

    char* w = (char*)d_ws;
    auto alloc = [&](size_t bytes) {
        void* p = (void*)w;
        w += (bytes + 255) & ~(size_t)255;
        return p;
    };
    int*            counts = (int*)           alloc((size_t)N * 4);
    int*            pos    = (int*)           alloc((size_t)N * 4);
    int*            bsums  = (int*)           alloc(4096);
    int*            spack  = (int*)           alloc((size_t)E * 4);
    unsigned short* Wt     = (unsigned short*)alloc((size_t)2 * 256 * DD * 2);
    unsigned short* rW     = (unsigned short*)alloc((size_t)R * DD * 2);
    unsigned short* hWn    = (unsigned short*)alloc((size_t)N * DD * 2);
    unsigned short* loopm  = (unsigned short*)alloc((size_t)N * DD * 2);
    unsigned short* hbf    = (unsigned short*)alloc((size_t)N * DD * 2);

    int nb = (N + SCAN_ELEMS - 1) / SCAN_ELEMS;

    // CSR build (reused by both layers)
    init_k<<<64 + (N + 255) / 256, 256, 0, stream>>>(Wn, Wl, Wt, counts, N);
    hist_k<<<(E + 255) / 256, 256, 0, stream>>>(edst, counts, E);
    block_reduce_k<<<nb, SCAN_BS, 0, stream>>>(counts, bsums, N);
    scan_bsums_k<<<1, SCAN_BS, 0, stream>>>(bsums, nb);
    scan_write_k<<<nb, SCAN_BS, 0, stream>>>(counts, bsums, pos, N);
    fill_k<<<(E + 255) / 256, 256, 0, stream>>>(esrc, edst, erel, pos, spack, E);
    // after fill_k: pos[r] == segment end, counts[r] == segment length

    int gemm_blocks = (N + R + 63) / 64;
    int agg_blocks  = (N * 16 + 255) / 256;

    // layer 1: fp32 node feats in, bf16 h out
    gemm_dual_mfma_k<false><<<gemm_blocks, 256, 0, stream>>>(
        node, rel_emb, Wt, hWn, loopm, rW, N, R);
    aggregate_k<true><<<agg_blocks, 256, 0, stream>>>(
        hWn, rW, spack, pos, counts, loopm, norm,
        node, nullptr, We, hbf, nullptr, N);

    // layer 2: bf16 h in, fp32 out
    gemm_dual_mfma_k<true><<<gemm_blocks, 256, 0, stream>>>(
        hbf, rel_emb, Wt + (size_t)256 * DD, hWn, loopm, rW, N, R);
    aggregate_k<false><<<agg_blocks, 256, 0, stream>>>(
        hWn, rW, spack, pos, counts, loopm, norm,
        nullptr, hbf, We + (size_t)DD * DD, nullptr, out, N);
}

// Round 6
// 158.384 us; speedup vs baseline: 6.8021x; 1.0497x over previous
//
#include <hip/hip_runtime.h>

#define DD 128
static constexpr float SLOPE = (1.0f/8.0f + 1.0f/3.0f) * 0.5f;  // rrelu eval slope

typedef __attribute__((ext_vector_type(8))) short bf16x8;
typedef __attribute__((ext_vector_type(4))) float f32x4;

__device__ inline unsigned short f2bf(float x) {
    unsigned u = __builtin_bit_cast(unsigned, x);
    unsigned r = (u + 0x7FFFu + ((u >> 16) & 1u)) >> 16;
    return (unsigned short)r;
}
__device__ inline float bflo(unsigned u) {  // low bf16 -> f32
    unsigned v = u << 16; return __builtin_bit_cast(float, v);
}
__device__ inline float bfhi(unsigned u) {  // high bf16 -> f32
    unsigned v = u & 0xFFFF0000u; return __builtin_bit_cast(float, v);
}
__device__ inline float2 bf2f2(unsigned u) {
    return make_float2(bflo(u), bfhi(u));
}

// ---- init: zero counts + build Wt + convert node/rel_emb -> hbf (bf16) ----
// blocks [0,64): Wt build; [64, 64+NB): zero counts; rest: fp32->bf16 convert.
__global__ __launch_bounds__(256) void init_k(
    const float* __restrict__ Wn, const float* __restrict__ Wl,
    const float* __restrict__ node, const float* __restrict__ rel_emb,
    unsigned short* __restrict__ Wt, int* __restrict__ counts,
    unsigned short* __restrict__ hbf, int N, int R, int NB)
{
    int b = blockIdx.x;
    if (b < 64) {
        int i = b * 256 + threadIdx.x;        // 0..16383, 4 k-elems each
        int l = i >> 13;
        int rem = i & 8191;
        int n = rem >> 5;
        int k0 = (rem & 31) * 4;
        const float* src = (n < 128) ? (Wn + l * DD * DD + n)
                                     : (Wl + l * DD * DD + (n - 128));
        unsigned short o0 = f2bf(src[(k0 + 0) * DD]);
        unsigned short o1 = f2bf(src[(k0 + 1) * DD]);
        unsigned short o2 = f2bf(src[(k0 + 2) * DD]);
        unsigned short o3 = f2bf(src[(k0 + 3) * DD]);
        *(ushort4*)&Wt[((size_t)l * 256 + n) * DD + k0] = make_ushort4(o0, o1, o2, o3);
    } else if (b < 64 + NB) {
        int i = (b - 64) * 256 + threadIdx.x;
        if (i < N) counts[i] = 0;
    } else {
        // convert: chunk c covers 8 elems; rows 0..N-1 from node, N.. from rel
        long c = (long)(b - 64 - NB) * 256 + threadIdx.x;
        long total = (long)(N + R) * 16;
        if (c >= total) return;
        long r = c >> 4;
        int  ch = (int)(c & 15);
        const float* s = (r < N) ? (node + r * DD + ch * 8)
                                 : (rel_emb + (r - N) * DD + ch * 8);
        float4 v0 = *(const float4*)s;
        float4 v1 = *(const float4*)(s + 4);
        union { bf16x8 v; unsigned short u[8]; } t;
        t.u[0] = f2bf(v0.x); t.u[1] = f2bf(v0.y);
        t.u[2] = f2bf(v0.z); t.u[3] = f2bf(v0.w);
        t.u[4] = f2bf(v1.x); t.u[5] = f2bf(v1.y);
        t.u[6] = f2bf(v1.z); t.u[7] = f2bf(v1.w);
        *(bf16x8*)&hbf[r * DD + ch * 8] = t.v;
    }
}

// ---------------- CSR build ----------------

__global__ __launch_bounds__(256) void hist_k(const int* __restrict__ dst,
                                              int* __restrict__ counts, int E) {
    int i = blockIdx.x * 256 + threadIdx.x;
    if (i < E) atomicAdd(&counts[dst[i]], 1);
}

#define SCAN_BS 256
#define SCAN_ELEMS 1024

__global__ __launch_bounds__(SCAN_BS) void block_reduce_k(const int* __restrict__ counts,
                                                          int* __restrict__ bsums, int N) {
    __shared__ int sm[SCAN_BS];
    int base = blockIdx.x * SCAN_ELEMS;
    int s = 0;
    for (int j = 0; j < 4; j++) {
        int idx = base + j * SCAN_BS + threadIdx.x;
        if (idx < N) s += counts[idx];
    }
    sm[threadIdx.x] = s; __syncthreads();
    for (int off = SCAN_BS / 2; off > 0; off >>= 1) {
        if (threadIdx.x < off) sm[threadIdx.x] += sm[threadIdx.x + off];
        __syncthreads();
    }
    if (threadIdx.x == 0) bsums[blockIdx.x] = sm[0];
}

__global__ __launch_bounds__(SCAN_BS) void scan_bsums_k(int* __restrict__ bsums, int nb) {
    __shared__ int sm[SCAN_BS];
    int v = threadIdx.x < nb ? bsums[threadIdx.x] : 0;
    sm[threadIdx.x] = v; __syncthreads();
    for (int off = 1; off < SCAN_BS; off <<= 1) {
        int t = threadIdx.x >= off ? sm[threadIdx.x - off] : 0;
        __syncthreads();
        sm[threadIdx.x] += t;
        __syncthreads();
    }
    if (threadIdx.x < nb) bsums[threadIdx.x] = sm[threadIdx.x] - v;  // exclusive
}

__global__ __launch_bounds__(SCAN_BS) void scan_write_k(const int* __restrict__ counts,
                                                        const int* __restrict__ bsums,
                                                        int* __restrict__ pos, int N) {
    __shared__ int sm[SCAN_BS];
    int base = blockIdx.x * SCAN_ELEMS + threadIdx.x * 4;
    int c[4]; int s = 0;
    for (int j = 0; j < 4; j++) {
        int idx = base + j;
        c[j] = idx < N ? counts[idx] : 0;
        s += c[j];
    }
    sm[threadIdx.x] = s; __syncthreads();
    for (int off = 1; off < SCAN_BS; off <<= 1) {
        int t = threadIdx.x >= off ? sm[threadIdx.x - off] : 0;
        __syncthreads();
        sm[threadIdx.x] += t;
        __syncthreads();
    }
    int run = bsums[blockIdx.x] + sm[threadIdx.x] - s;  // exclusive offset
    for (int j = 0; j < 4; j++) {
        int idx = base + j;
        if (idx < N) pos[idx] = run;
        run += c[j];
    }
}

// pack src | (rel<<17): src < 2^17, rel < 460 < 2^9
__global__ __launch_bounds__(256) void fill_k(const int* __restrict__ esrc,
                                              const int* __restrict__ edst,
                                              const int* __restrict__ erel,
                                              int* __restrict__ pos,
                                              int* __restrict__ spack, int E) {
    int e = blockIdx.x * 256 + threadIdx.x;
    if (e >= E) return;
    int d = edst[e];
    int slot = atomicAdd(&pos[d], 1);
    spack[slot] = esrc[e] | (erel[e] << 17);
}

// ---------------- MFMA dual GEMM: Abf @ [Wn | Wl] -> (hWn|loopm), rW ----
// BM=64 rows/block, BN=256 cols, 4 waves (64 cols each).
// A rows direct global->VGPR (bf16); W staged in swizzled LDS; epilogue via
// LDS bounce for coalesced 16B stores.
__global__ __launch_bounds__(256) void gemm_dual_mfma_k(
    const unsigned short* __restrict__ Abf,  // [N+R][128] bf16 (h rows ++ rel rows)
    const unsigned short* __restrict__ Wt,   // [256][128] bf16, this layer
    unsigned short* __restrict__ hWn,        // [N][128] bf16
    unsigned short* __restrict__ loopm,      // [N][128] bf16
    unsigned short* __restrict__ rW,         // [R][128] bf16
    int N, int M)                            // M = N + R
{
    __shared__ unsigned short Wsm[256 * DD];   // 64 KB, XOR-swizzled rows
    int tid = threadIdx.x;
    int row0 = blockIdx.x * 64;
    int w = tid >> 6, lane = tid & 63;
    int g = lane >> 4, q = lane & 15;

    // issue A-fragment loads first (latency hides under W staging + barrier)
    // a[s][mi] = A[row0+mi*16+q][k = s*32 + g*8 .. +7]
    bf16x8 a[4][4];
    #pragma unroll
    for (int s = 0; s < 4; ++s)
        #pragma unroll
        for (int mi = 0; mi < 4; ++mi) {
            int r = row0 + mi * 16 + q;
            if (r >= M) r = M - 1;                  // tail clamp (stores masked)
            a[s][mi] = *(const bf16x8*)&Abf[(size_t)r * DD + s * 32 + g * 8];
        }

    // stage Wt (bf16 [n][k]): linear global read, swizzled LDS write
    #pragma unroll
    for (int it = 0; it < 16; ++it) {
        int ci = it * 256 + tid;                 // 16B chunk index 0..4095
        uint4 wv = *(const uint4*)((const char*)Wt + (size_t)ci * 16);
        int lin = ci * 16;
        int row = lin >> 8;
        int off = lin ^ ((row & 7) << 4);
        *(uint4*)((char*)Wsm + off) = wv;
    }
    __syncthreads();

    int sw = (q & 7) << 4;
    f32x4 acc[4][4];
    #pragma unroll
    for (int mi = 0; mi < 4; ++mi)
        #pragma unroll
        for (int ni = 0; ni < 4; ++ni)
            acc[mi][ni] = (f32x4){0.f, 0.f, 0.f, 0.f};

    #pragma unroll
    for (int s = 0; s < 4; ++s) {               // k = 32s .. 32s+31
        int off = 64 * s + 16 * g;              // byte offset within row
        bf16x8 b[4];
        #pragma unroll
        for (int ni = 0; ni < 4; ++ni) {
            int n = w * 64 + ni * 16 + q;
            b[ni] = *(const bf16x8*)((const char*)Wsm + n * 256 + (off ^ sw));
        }
        #pragma unroll
        for (int mi = 0; mi < 4; ++mi)
            #pragma unroll
            for (int ni = 0; ni < 4; ++ni)
                acc[mi][ni] = __builtin_amdgcn_mfma_f32_16x16x32_bf16(
                    a[s][mi], b[ni], acc[mi][ni], 0, 0, 0);
    }
    __syncthreads();   // all waves done reading Wsm; reuse as C-bounce buffer

    // C/D layout: col=lane&15, row=(lane>>4)*4+reg [m89].
    // Write acc -> LDS bf16 [64 rows][256 cols], 32B-window XOR swizzle
    // (window id = (row>>2)&7: distinct per g within an instr -> conflict-free)
    char* Cb = (char*)Wsm;
    #pragma unroll
    for (int mi = 0; mi < 4; ++mi)
        #pragma unroll
        for (int ni = 0; ni < 4; ++ni) {
            int col = w * 64 + ni * 16 + q;
            #pragma unroll
            for (int j = 0; j < 4; ++j) {
                int row = mi * 16 + g * 4 + j;
                int off = row * 512 + ((col * 2) ^ (((row >> 2) & 7) << 5));
                *(unsigned short*)(Cb + off) = f2bf(acc[mi][ni][j]);
            }
        }
    __syncthreads();

    // cooperative readback: 64 rows x 32 chunks(16B) = 2048; 8 per thread
    #pragma unroll
    for (int c0 = 0; c0 < 8; ++c0) {
        int c = c0 * 256 + tid;
        int row = c >> 5, colc = c & 31;
        int off = row * 512 + ((colc * 16) ^ (((row >> 2) & 7) << 5));
        bf16x8 v = *(const bf16x8*)(Cb + off);
        int grow = row0 + row;
        int col = colc * 8;
        if (grow < N) {
            if (col < DD) *(bf16x8*)&hWn[(size_t)grow * DD + col] = v;
            else          *(bf16x8*)&loopm[(size_t)grow * DD + col - DD] = v;
        } else if (grow < M && col < DD) {
            *(bf16x8*)&rW[(size_t)(grow - N) * DD + col] = v;
        }
    }
}

// ---------------- gather aggregate + fused finalize + fused evolve-fixup ----
// 16 lanes per dst row (16B/lane dwordx4 gathers), 4 rows per wave.
// count==0 rows (~e^-10 of N): o = rrelu(hbf[r] @ We) computed inline.
#define ACC8(A, B) do { \
    acc0 += bf2f2((A).x) + bf2f2((B).x); \
    acc1 += bf2f2((A).y) + bf2f2((B).y); \
    acc2 += bf2f2((A).z) + bf2f2((B).z); \
    acc3 += bf2f2((A).w) + bf2f2((B).w); \
} while (0)

template<bool LAYER1>
__global__ __launch_bounds__(256) void aggregate_k(
    const unsigned short* __restrict__ hWn, const unsigned short* __restrict__ rW,
    const int* __restrict__ spack,
    const int* __restrict__ endp, const int* __restrict__ counts,
    const unsigned short* __restrict__ loopm, const float* __restrict__ norm,
    const unsigned short* __restrict__ hbf,    // prev h (bf16)
    const float* __restrict__ We,              // this layer's W_evolve
    unsigned short* __restrict__ hbf_out,      // LAYER1 output (bf16)
    float* __restrict__ fout,                  // !LAYER1 output (fp32)
    int N)
{
    int t = blockIdx.x * 256 + threadIdx.x;
    int r = t >> 4;              // 16 lanes per row
    if (r >= N) return;
    int sl = t & 15;             // sub-lane: bytes sl*16 of the 256B bf16 row
    int cnt = counts[r];
    int end = endp[r];
    size_t boff = (size_t)sl * 16;

    float o[8];
    if (cnt == 0) {
        // evolve self-loop: o[j] = sum_k hbf[r][k] * We[k][sl*8+j]
        #pragma unroll
        for (int j = 0; j < 8; ++j) o[j] = 0.f;
        for (int k = 0; k < DD; ++k) {
            float hk = bflo((unsigned)hbf[(size_t)r * DD + k]);
            const float* wr = We + (size_t)k * DD + sl * 8;
            float4 w0 = *(const float4*)wr;
            float4 w1 = *(const float4*)(wr + 4);
            o[0] += hk * w0.x; o[1] += hk * w0.y;
            o[2] += hk * w0.z; o[3] += hk * w0.w;
            o[4] += hk * w1.x; o[5] += hk * w1.y;
            o[6] += hk * w1.z; o[7] += hk * w1.w;
        }
    } else {
        const char* hb = (const char*)hWn;
        const char* rb = (const char*)rW;
        int beg = end - cnt;
        float2 acc0 = make_float2(0.f, 0.f), acc1 = acc0, acc2 = acc0, acc3 = acc0;

        int i = beg;
        for (; i + 4 <= end; i += 4) {
            int p0 = spack[i], p1 = spack[i + 1], p2 = spack[i + 2], p3 = spack[i + 3];
            uint4 a0 = *(const uint4*)(hb + (size_t)(p0 & 0x1FFFF) * 256 + boff);
            uint4 b0 = *(const uint4*)(rb + (size_t)(p0 >> 17) * 256 + boff);
            uint4 a1 = *(const uint4*)(hb + (size_t)(p1 & 0x1FFFF) * 256 + boff);
            uint4 b1 = *(const uint4*)(rb + (size_t)(p1 >> 17) * 256 + boff);
            uint4 a2 = *(const uint4*)(hb + (size_t)(p2 & 0x1FFFF) * 256 + boff);
            uint4 b2 = *(const uint4*)(rb + (size_t)(p2 >> 17) * 256 + boff);
            uint4 a3 = *(const uint4*)(hb + (size_t)(p3 & 0x1FFFF) * 256 + boff);
            uint4 b3 = *(const uint4*)(rb + (size_t)(p3 >> 17) * 256 + boff);
            ACC8(a0, b0); ACC8(a1, b1); ACC8(a2, b2); ACC8(a3, b3);
        }
        for (; i + 2 <= end; i += 2) {
            int p0 = spack[i], p1 = spack[i + 1];
            uint4 a0 = *(const uint4*)(hb + (size_t)(p0 & 0x1FFFF) * 256 + boff);
            uint4 b0 = *(const uint4*)(rb + (size_t)(p0 >> 17) * 256 + boff);
            uint4 a1 = *(const uint4*)(hb + (size_t)(p1 & 0x1FFFF) * 256 + boff);
            uint4 b1 = *(const uint4*)(rb + (size_t)(p1 >> 17) * 256 + boff);
            ACC8(a0, b0); ACC8(a1, b1);
        }
        if (i < end) {
            int p0 = spack[i];
            uint4 a0 = *(const uint4*)(hb + (size_t)(p0 & 0x1FFFF) * 256 + boff);
            uint4 b0 = *(const uint4*)(rb + (size_t)(p0 >> 17) * 256 + boff);
            ACC8(a0, b0);
        }

        float nv = norm[r];
        uint4 lu = *(const uint4*)((const char*)loopm + (size_t)r * 256 + boff);
        o[0] = acc0.x * nv + bflo(lu.x);
        o[1] = acc0.y * nv + bfhi(lu.x);
        o[2] = acc1.x * nv + bflo(lu.y);
        o[3] = acc1.y * nv + bfhi(lu.y);
        o[4] = acc2.x * nv + bflo(lu.z);
        o[5] = acc2.y * nv + bfhi(lu.z);
        o[6] = acc3.x * nv + bflo(lu.w);
        o[7] = acc3.y * nv + bfhi(lu.w);
    }

    #pragma unroll
    for (int j = 0; j < 8; ++j) o[j] = o[j] >= 0.f ? o[j] : SLOPE * o[j];

    if constexpr (LAYER1) {
        union { bf16x8 v; unsigned short u[8]; } t2;
        #pragma unroll
        for (int j = 0; j < 8; ++j) t2.u[j] = f2bf(o[j]);
        *(bf16x8*)&hbf_out[(size_t)r * DD + sl * 8] = t2.v;
    } else {
        float* op = &fout[(size_t)r * DD + sl * 8];
        *(float4*)op       = make_float4(o[0], o[1], o[2], o[3]);
        *(float4*)(op + 4) = make_float4(o[4], o[5], o[6], o[7]);
    }
}

extern "C" void kernel_launch(void* const* d_in, const int* in_sizes, int n_in,
                              void* d_out, int out_size, void* d_ws, size_t ws_size,
                              hipStream_t stream) {
    const float* node    = (const float*)d_in[0];
    const float* rel_emb = (const float*)d_in[1];
    const float* norm    = (const float*)d_in[2];
    const int*   esrc    = (const int*)d_in[3];
    const int*   edst    = (const int*)d_in[4];
    const int*   erel    = (const int*)d_in[5];
    const float* Wn      = (const float*)d_in[6];
    const float* Wl      = (const float*)d_in[7];
    const float* We      = (const float*)d_in[8];
    int N = in_sizes[0] / DD;
    int R = in_sizes[1] / DD;
    int E = in_sizes[3];
    float* out = (float*)d_out;

    char* w = (char*)d_ws;
    auto alloc = [&](size_t bytes) {
        void* p = (void*)w;
        w += (bytes + 255) & ~(size_t)255;
        return p;
    };
    int*            counts = (int*)           alloc((size_t)N * 4);
    int*            pos    = (int*)           alloc((size_t)N * 4);
    int*            bsums  = (int*)           alloc(4096);
    int*            spack  = (int*)           alloc((size_t)E * 4);
    unsigned short* Wt     = (unsigned short*)alloc((size_t)2 * 256 * DD * 2);
    unsigned short* rW     = (unsigned short*)alloc((size_t)R * DD * 2);
    unsigned short* hWn    = (unsigned short*)alloc((size_t)N * DD * 2);
    unsigned short* loopm  = (unsigned short*)alloc((size_t)N * DD * 2);
    unsigned short* hbf    = (unsigned short*)alloc((size_t)(N + R) * DD * 2);

    int nb = (N + SCAN_ELEMS - 1) / SCAN_ELEMS;
    int NB = (N + 255) / 256;
    int CB = (int)(((long)(N + R) * 16 + 255) / 256);
    int M = N + R;

    // init (W transpose+cvt, counts zero, h/rel -> bf16) + CSR build
    init_k<<<64 + NB + CB, 256, 0, stream>>>(Wn, Wl, node, rel_emb,
                                             Wt, counts, hbf, N, R, NB);
    hist_k<<<(E + 255) / 256, 256, 0, stream>>>(edst, counts, E);
    block_reduce_k<<<nb, SCAN_BS, 0, stream>>>(counts, bsums, N);
    scan_bsums_k<<<1, SCAN_BS, 0, stream>>>(bsums, nb);
    scan_write_k<<<nb, SCAN_BS, 0, stream>>>(counts, bsums, pos, N);
    fill_k<<<(E + 255) / 256, 256, 0, stream>>>(esrc, edst, erel, pos, spack, E);
    // after fill_k: pos[r] == segment end, counts[r] == segment length

    int gemm_blocks = (M + 63) / 64;
    int agg_blocks  = (N * 16 + 255) / 256;

    // layer 1: bf16 h in (from init cvt), bf16 h out (in-place rows [0,N))
    gemm_dual_mfma_k<<<gemm_blocks, 256, 0, stream>>>(
        hbf, Wt, hWn, loopm, rW, N, M);
    aggregate_k<true><<<agg_blocks, 256, 0, stream>>>(
        hWn, rW, spack, pos, counts, loopm, norm, hbf, We, hbf, nullptr, N);

    // layer 2: bf16 h in, fp32 out
    gemm_dual_mfma_k<<<gemm_blocks, 256, 0, stream>>>(
        hbf, Wt + (size_t)256 * DD, hWn, loopm, rW, N, M);
    aggregate_k<false><<<agg_blocks, 256, 0, stream>>>(
        hWn, rW, spack, pos, counts, loopm, norm, hbf,
        We + (size_t)DD * DD, nullptr, out, N);
}